// Round 2
// baseline (975.953 us; speedup 1.0000x reference)
//
#include <hip/hip_runtime.h>
#include <hip/hip_bf16.h>

typedef unsigned short u16;
typedef __bf16 bf16x8 __attribute__((ext_vector_type(8)));
typedef float floatx4 __attribute__((ext_vector_type(4)));

static constexpr int D = 128;

// ---------------- zero workspace ----------------
__global__ void zero_ws_kernel(uint4* __restrict__ p, int n16) {
    int i = blockIdx.x * blockDim.x + threadIdx.x;
    int stride = gridDim.x * blockDim.x;
    uint4 z = make_uint4(0u, 0u, 0u, 0u);
    for (; i < n16; i += stride) p[i] = z;
}

// ---------------- convert x fp32 -> bf16 ----------------
__global__ void convert_x_kernel(const float4* __restrict__ x, ushort4* __restrict__ xb, int n4) {
    int i = blockIdx.x * blockDim.x + threadIdx.x;
    int stride = gridDim.x * blockDim.x;
    for (; i < n4; i += stride) {
        float4 v = x[i];
        ushort4 o;
        o.x = __hip_bfloat16_raw(__float2bfloat16(v.x)).x;
        o.y = __hip_bfloat16_raw(__float2bfloat16(v.y)).x;
        o.z = __hip_bfloat16_raw(__float2bfloat16(v.z)).x;
        o.w = __hip_bfloat16_raw(__float2bfloat16(v.w)).x;
        xb[i] = o;
    }
}

// ---------------- per-dst counts ----------------
__global__ void count_kernel(const int* __restrict__ dst, int* __restrict__ counts, int E) {
    int i = blockIdx.x * blockDim.x + threadIdx.x;
    if (i < E) atomicAdd(&counts[dst[i]], 1);
}

// ---------------- pack fp32 weight into bf16 MFMA B-fragment order ----------------
// Wp[((s*8+t)*64+l)*8 + j] = B[k][n],  k = 32*s + (l>>4)*8 + j,  n = 16*t + (l&15)
// edge weights: B[k][n] = W[k*128+n];  WC (transposed=1): B[k][n] = WC[n*K+k]
__global__ void pack_kernel(const float* __restrict__ W, u16* __restrict__ out, int K, int transposed) {
    int c = blockIdx.x * blockDim.x + threadIdx.x;
    if (c >= K * 16) return;
    int s = c >> 9, rem = c & 511, t = rem >> 6, l = rem & 63;
    int kbase = 32 * s + ((l >> 4) * 8);
    int n = 16 * t + (l & 15);
#pragma unroll
    for (int j = 0; j < 8; ++j) {
        int k = kbase + j;
        float w = transposed ? W[n * K + k] : W[k * D + n];
        out[(size_t)c * 8 + j] = __hip_bfloat16_raw(__float2bfloat16(w)).x;
    }
}

// ---------------- gathered MFMA GEMM ----------------
// Edge mode (!FINAL): C[e,:] = xb[src[e*ARITY..]] (concat) @ W; agg[dst[e],:] += C[e,:]/counts[dst[e]]
// Final mode: out[n,:] = xb[n,:]@WC^T + bC + agg[n,:]   (fp32 out)
template <int ARITY, bool FINAL>
__global__ __launch_bounds__(256) void gemm_kernel(
    const u16* __restrict__ xb,
    const int* __restrict__ src,
    const int* __restrict__ dst,
    const int* __restrict__ counts,
    const u16* __restrict__ Wp,
    float* __restrict__ agg,
    const float* __restrict__ bC,
    float* __restrict__ out,
    int M) {
    constexpr int KSTEPS = FINAL ? 2 : ARITY * 2;  // BK = 64
    alignas(16) __shared__ u16 As[128][72];        // 128 rows x 64 cols, +8 pad
    alignas(16) __shared__ u16 Bs[8192];           // 64x128 bf16 tile, fragment-packed

    const int tid = threadIdx.x;
    const int wave = tid >> 6;
    const int lane = tid & 63;
    const int m0 = blockIdx.x * 128;

    floatx4 acc[2][8];
#pragma unroll
    for (int s = 0; s < 2; ++s)
#pragma unroll
        for (int t = 0; t < 8; ++t) acc[s][t] = floatx4{0.f, 0.f, 0.f, 0.f};

    for (int ks = 0; ks < KSTEPS; ++ks) {
        // ---- stage A tile: columns [ks*64, ks*64+64) of gathered rows ----
        const int i_src = ks >> 1;             // which source row of the concat
        const int halfofs = (ks & 1) * 64;     // element offset within x row
#pragma unroll
        for (int it = 0; it < 4; ++it) {
            int chunk = tid + it * 256;        // 1024 chunks of 16B
            int row = chunk >> 3, part = chunk & 7;
            int e = m0 + row;
            int r;
            if constexpr (FINAL)
                r = (e < M) ? e : 0;
            else
                r = (e < M) ? src[(size_t)e * ARITY + i_src] : 0;
            *(uint4*)(&As[row][part * 8]) =
                *(const uint4*)(xb + (size_t)r * D + halfofs + part * 8);
        }
        // ---- stage B tile: 16KB contiguous from packed W ----
        {
            const uint4* sB = (const uint4*)(Wp + (size_t)ks * 8192);
            uint4* dB = (uint4*)Bs;
#pragma unroll
            for (int it = 0; it < 4; ++it) dB[tid + it * 256] = sB[tid + it * 256];
        }
        __syncthreads();
        // ---- compute: 2 sub-steps of K=32 ----
#pragma unroll
        for (int sub = 0; sub < 2; ++sub) {
            bf16x8 bfrag[8];
#pragma unroll
            for (int t = 0; t < 8; ++t)
                bfrag[t] = *(const bf16x8*)(&Bs[((sub * 8 + t) * 64 + lane) * 8]);
#pragma unroll
            for (int strip = 0; strip < 2; ++strip) {
                int row = wave * 32 + strip * 16 + (lane & 15);
                bf16x8 afrag = *(const bf16x8*)(&As[row][sub * 32 + ((lane >> 4) * 8)]);
#pragma unroll
                for (int t = 0; t < 8; ++t)
                    acc[strip][t] = __builtin_amdgcn_mfma_f32_16x16x32_bf16(
                        afrag, bfrag[t], acc[strip][t], 0, 0, 0);
            }
        }
        __syncthreads();
    }

    // ---- epilogue ----
    // C/D layout: col = 16*t + (lane&15), row(within 16) = (lane>>4)*4 + r
#pragma unroll
    for (int strip = 0; strip < 2; ++strip) {
#pragma unroll
        for (int r = 0; r < 4; ++r) {
            int row = wave * 32 + strip * 16 + (lane >> 4) * 4 + r;
            int e = m0 + row;
            if (e >= M) continue;
            if constexpr (!FINAL) {
                int dnode = dst[e];
                float norm = 1.0f / (float)counts[dnode];
                float* arow = agg + (size_t)dnode * D;
#pragma unroll
                for (int t = 0; t < 8; ++t)
                    unsafeAtomicAdd(&arow[16 * t + (lane & 15)], acc[strip][t][r] * norm);
            } else {
                size_t base = (size_t)e * D;
#pragma unroll
                for (int t = 0; t < 8; ++t) {
                    int col = 16 * t + (lane & 15);
                    out[base + col] = acc[strip][t][r] + bC[col] + agg[base + col];
                }
            }
        }
    }
}

extern "C" void kernel_launch(void* const* d_in, const int* in_sizes, int n_in,
                              void* d_out, int out_size, void* d_ws, size_t ws_size,
                              hipStream_t stream) {
    const float* x = (const float*)d_in[0];
    const int* src0 = (const int*)d_in[1];
    const int* dst0 = (const int*)d_in[2];
    const int* src1 = (const int*)d_in[3];
    const int* dst1 = (const int*)d_in[4];
    const int* src2 = (const int*)d_in[5];
    const int* dst2 = (const int*)d_in[6];
    const float* WA0 = (const float*)d_in[7];
    const float* WA1 = (const float*)d_in[8];
    const float* WA2 = (const float*)d_in[9];
    const float* WC = (const float*)d_in[10];
    const float* bC = (const float*)d_in[11];

    const int N = in_sizes[0] / D;   // 100000 nodes
    const int E = in_sizes[2];       // 500000 edges per type (dst0 length)

    char* ws = (char*)d_ws;
    float* agg = (float*)ws;                          // N*D fp32
    size_t aggBytes = (size_t)N * D * sizeof(float);
    int* counts0 = (int*)(ws + aggBytes);
    int* counts1 = counts0 + N;
    int* counts2 = counts1 + N;
    size_t ofs = aggBytes + (size_t)3 * N * sizeof(int);
    u16* xb = (u16*)(ws + ofs);                       // N*D bf16
    ofs += (size_t)N * D * sizeof(u16);
    u16* Wp0 = (u16*)(ws + ofs);
    u16* Wp1 = Wp0 + 128 * D;
    u16* Wp2 = Wp1 + 256 * D;
    u16* WpC = Wp2 + 384 * D;

    // zero agg + counts
    int n16 = (int)((aggBytes + (size_t)3 * N * sizeof(int)) / 16);
    zero_ws_kernel<<<1024, 256, 0, stream>>>((uint4*)ws, n16);

    // convert x to bf16
    convert_x_kernel<<<1024, 256, 0, stream>>>((const float4*)x, (ushort4*)xb, N * D / 4);

    // pack weights into bf16 fragment order
    pack_kernel<<<(128 * 16 + 255) / 256, 256, 0, stream>>>(WA0, Wp0, 128, 0);
    pack_kernel<<<(256 * 16 + 255) / 256, 256, 0, stream>>>(WA1, Wp1, 256, 0);
    pack_kernel<<<(384 * 16 + 255) / 256, 256, 0, stream>>>(WA2, Wp2, 384, 0);
    pack_kernel<<<(128 * 16 + 255) / 256, 256, 0, stream>>>(WC, WpC, 128, 1);

    // per-dst counts per edge type
    int cb = (E + 255) / 256;
    count_kernel<<<cb, 256, 0, stream>>>(dst0, counts0, E);
    count_kernel<<<cb, 256, 0, stream>>>(dst1, counts1, E);
    count_kernel<<<cb, 256, 0, stream>>>(dst2, counts2, E);

    // edge-type GEMMs with fused normalize + scatter-add
    int gb = (E + 127) / 128;
    gemm_kernel<1, false><<<gb, 256, 0, stream>>>(xb, src0, dst0, counts0, Wp0, agg, nullptr, nullptr, E);
    gemm_kernel<2, false><<<gb, 256, 0, stream>>>(xb, src1, dst1, counts1, Wp1, agg, nullptr, nullptr, E);
    gemm_kernel<3, false><<<gb, 256, 0, stream>>>(xb, src2, dst2, counts2, Wp2, agg, nullptr, nullptr, E);

    // final: out = x @ WC^T + bC + agg
    gemm_kernel<1, true><<<(N + 127) / 128, 256, 0, stream>>>(xb, nullptr, nullptr, nullptr, WpC, agg, bC, (float*)d_out, N);
}

// Round 3
// 708.600 us; speedup vs baseline: 1.3773x; 1.3773x over previous
//
#include <hip/hip_runtime.h>
#include <hip/hip_bf16.h>

typedef unsigned short u16;
typedef __bf16 bf16x8 __attribute__((ext_vector_type(8)));
typedef float floatx4 __attribute__((ext_vector_type(4)));

static constexpr int D = 128;

__device__ inline float bflo(unsigned u) { return __uint_as_float(u << 16); }
__device__ inline float bfhi(unsigned u) { return __uint_as_float(u & 0xffff0000u); }
__device__ inline unsigned packbf(float a, float b) {
    unsigned lo = __hip_bfloat16_raw(__float2bfloat16(a)).x;
    unsigned hi = __hip_bfloat16_raw(__float2bfloat16(b)).x;
    return lo | (hi << 16);
}

// ---------------- zero ints ----------------
__global__ void zero_int_kernel(int* __restrict__ p, int n) {
    int i = blockIdx.x * blockDim.x + threadIdx.x;
    int stride = gridDim.x * blockDim.x;
    for (; i < n; i += stride) p[i] = 0;
}

// ---------------- convert x fp32 -> bf16 ----------------
__global__ void convert_x_kernel(const float4* __restrict__ x, ushort4* __restrict__ xb, int n4) {
    int i = blockIdx.x * blockDim.x + threadIdx.x;
    int stride = gridDim.x * blockDim.x;
    for (; i < n4; i += stride) {
        float4 v = x[i];
        ushort4 o;
        o.x = __hip_bfloat16_raw(__float2bfloat16(v.x)).x;
        o.y = __hip_bfloat16_raw(__float2bfloat16(v.y)).x;
        o.z = __hip_bfloat16_raw(__float2bfloat16(v.z)).x;
        o.w = __hip_bfloat16_raw(__float2bfloat16(v.w)).x;
        xb[i] = o;
    }
}

// ---------------- per-dst counts ----------------
__global__ void count_kernel(const int* __restrict__ dst, int* __restrict__ counts, int E) {
    int i = blockIdx.x * blockDim.x + threadIdx.x;
    if (i < E) atomicAdd(&counts[dst[i]], 1);
}

// ---------------- exclusive scan (one block per edge type) ----------------
__global__ __launch_bounds__(1024) void scan_kernel(const int* __restrict__ counts,
                                                    int* __restrict__ offs,
                                                    int* __restrict__ cursor, int N) {
    int b = blockIdx.x;
    const int* cnt = counts + (size_t)b * N;
    int* of = offs + (size_t)b * (N + 1);
    int* cur = cursor + (size_t)b * N;
    int tid = threadIdx.x, lane = tid & 63, wv = tid >> 6;  // 16 waves
    __shared__ int lds[32];
    int carry = 0;
    for (int base = 0; base < N; base += 8192) {
        int idx0 = base + tid * 8;
        int v[8], s = 0;
#pragma unroll
        for (int j = 0; j < 8; ++j) {
            v[j] = (idx0 + j < N) ? cnt[idx0 + j] : 0;
            s += v[j];
        }
        int incl = s;
#pragma unroll
        for (int d = 1; d < 64; d <<= 1) {
            int t = __shfl_up(incl, d, 64);
            if (lane >= d) incl += t;
        }
        int wexcl = incl - s;
        if (lane == 63) lds[wv] = incl;
        __syncthreads();
        if (wv == 0 && lane < 16) {
            int w = lds[lane];
            int wi = w;
#pragma unroll
            for (int d = 1; d < 16; d <<= 1) {
                int t = __shfl_up(wi, d, 64);
                if (lane >= d) wi += t;
            }
            lds[lane] = wi - w;
            if (lane == 15) lds[16] = wi;
        }
        __syncthreads();
        int run = carry + lds[wv] + wexcl;
#pragma unroll
        for (int j = 0; j < 8; ++j) {
            if (idx0 + j < N) { of[idx0 + j] = run; cur[idx0 + j] = run; }
            run += v[j];
        }
        carry += lds[16];
        __syncthreads();
    }
    if (tid == 0) of[N] = carry;
}

// ---------------- CSR scatter ----------------
__global__ void scatter_kernel(const int* __restrict__ dst, int* __restrict__ cursor,
                               int* __restrict__ eids, int E) {
    int e = blockIdx.x * blockDim.x + threadIdx.x;
    if (e < E) {
        int pos = atomicAdd(&cursor[dst[e]], 1);
        eids[pos] = e;
    }
}

// ---------------- per-node aggregation of x rows ----------------
template <int A>
__device__ inline void agg_one(const u16* __restrict__ xb, const int* __restrict__ offs,
                               const int* __restrict__ eids, const int* __restrict__ src,
                               int n, int lane, u16* __restrict__ outp) {
    int o0 = offs[n], o1 = offs[n + 1];
    float2 acc[A];
#pragma unroll
    for (int s = 0; s < A; ++s) acc[s] = make_float2(0.f, 0.f);
    for (int j = o0; j < o1; ++j) {
        int eid = eids[j];
#pragma unroll
        for (int s = 0; s < A; ++s) {
            int r = src[eid * A + s];
            unsigned u = ((const unsigned*)(xb + (size_t)r * D))[lane];
            acc[s].x += bflo(u);
            acc[s].y += bfhi(u);
        }
    }
    float norm = (o1 > o0) ? 1.0f / (float)(o1 - o0) : 0.0f;
#pragma unroll
    for (int s = 0; s < A; ++s)
        ((unsigned*)(outp + s * D))[lane] = packbf(acc[s].x * norm, acc[s].y * norm);
}

__global__ __launch_bounds__(256) void aggregate_kernel(
    const u16* __restrict__ xb,
    const int* __restrict__ offs, const int* __restrict__ eids,
    const int* __restrict__ src0, const int* __restrict__ src1, const int* __restrict__ src2,
    u16* __restrict__ AG, int n0, int Nc, int N, int E) {
    int wave = (int)((blockIdx.x * 256 + threadIdx.x) >> 6);
    int lane = threadIdx.x & 63;
    int n = n0 + wave;
    if (wave >= Nc || n >= N) return;
    u16* outp = AG + (size_t)wave * 768;
    const int* offs1 = offs + (N + 1);
    const int* offs2 = offs + 2 * (N + 1);
    const int* eids1 = eids + E;
    const int* eids2 = eids + 2 * E;
    agg_one<1>(xb, offs, eids, src0, n, lane, outp + 0);
    agg_one<2>(xb, offs1, eids1, src1, n, lane, outp + 128);
    agg_one<3>(xb, offs2, eids2, src2, n, lane, outp + 384);
}

// ---------------- pack fp32 weight into bf16 MFMA B-fragment order ----------------
// out[c*8+j] for c=(s,t,l): B[k][n], k=32s+(l>>4)*8+j, n=16t+(l&15)
__global__ void pack_kernel(const float* __restrict__ W, u16* __restrict__ out, int K, int transposed) {
    int c = blockIdx.x * blockDim.x + threadIdx.x;
    if (c >= K * 16) return;
    int s = c >> 9, rem = c & 511, t = rem >> 6, l = rem & 63;
    int kbase = 32 * s + ((l >> 4) * 8);
    int n = 16 * t + (l & 15);
#pragma unroll
    for (int j = 0; j < 8; ++j) {
        int k = kbase + j;
        float w = transposed ? W[n * K + k] : W[k * D + n];
        out[(size_t)c * 8 + j] = __hip_bfloat16_raw(__float2bfloat16(w)).x;
    }
}

// ---------------- fused final GEMM: out = [x | AG] @ [WC^T; WA*] + bC ----------------
__global__ __launch_bounds__(256) void final_gemm_kernel(
    const u16* __restrict__ xb, const u16* __restrict__ AG, const u16* __restrict__ Wp,
    const float* __restrict__ bC, float* __restrict__ out, int n0, int M) {
    constexpr int KSTEPS = 14;  // 896 / 64
    alignas(16) __shared__ u16 As[128][72];
    alignas(16) __shared__ u16 Bs[8192];

    const int tid = threadIdx.x;
    const int wave = tid >> 6;
    const int lane = tid & 63;
    const int m0 = blockIdx.x * 128;

    floatx4 acc[2][8];
#pragma unroll
    for (int s = 0; s < 2; ++s)
#pragma unroll
        for (int t = 0; t < 8; ++t) acc[s][t] = floatx4{0.f, 0.f, 0.f, 0.f};

    for (int ks = 0; ks < KSTEPS; ++ks) {
#pragma unroll
        for (int it = 0; it < 4; ++it) {
            int chunk = tid + it * 256;
            int row = chunk >> 3, part = chunk & 7;
            int e = m0 + row;
            const u16* srcp;
            if (ks < 2) {
                int g = (e < M) ? (n0 + e) : n0;
                srcp = xb + (size_t)g * D + ks * 64;
            } else {
                int l = (e < M) ? e : 0;
                srcp = AG + (size_t)l * 768 + (ks - 2) * 64;
            }
            *(uint4*)(&As[row][part * 8]) = *(const uint4*)(srcp + part * 8);
        }
        {
            const uint4* sB = (const uint4*)(Wp + (size_t)ks * 8192);
            uint4* dB = (uint4*)Bs;
#pragma unroll
            for (int it = 0; it < 4; ++it) dB[tid + it * 256] = sB[tid + it * 256];
        }
        __syncthreads();
#pragma unroll
        for (int sub = 0; sub < 2; ++sub) {
            bf16x8 bfrag[8];
#pragma unroll
            for (int t = 0; t < 8; ++t)
                bfrag[t] = *(const bf16x8*)(&Bs[((sub * 8 + t) * 64 + lane) * 8]);
#pragma unroll
            for (int strip = 0; strip < 2; ++strip) {
                int row = wave * 32 + strip * 16 + (lane & 15);
                bf16x8 afrag = *(const bf16x8*)(&As[row][sub * 32 + ((lane >> 4) * 8)]);
#pragma unroll
                for (int t = 0; t < 8; ++t)
                    acc[strip][t] = __builtin_amdgcn_mfma_f32_16x16x32_bf16(
                        afrag, bfrag[t], acc[strip][t], 0, 0, 0);
            }
        }
        __syncthreads();
    }

#pragma unroll
    for (int strip = 0; strip < 2; ++strip) {
#pragma unroll
        for (int r = 0; r < 4; ++r) {
            int row = wave * 32 + strip * 16 + (lane >> 4) * 4 + r;
            int e = m0 + row;
            if (e >= M) continue;
            size_t base = (size_t)(n0 + e) * D;
#pragma unroll
            for (int t = 0; t < 8; ++t) {
                int col = 16 * t + (lane & 15);
                out[base + col] = acc[strip][t][r] + bC[col];
            }
        }
    }
}

extern "C" void kernel_launch(void* const* d_in, const int* in_sizes, int n_in,
                              void* d_out, int out_size, void* d_ws, size_t ws_size,
                              hipStream_t stream) {
    const float* x = (const float*)d_in[0];
    const int* src0 = (const int*)d_in[1];
    const int* dst0 = (const int*)d_in[2];
    const int* src1 = (const int*)d_in[3];
    const int* dst1 = (const int*)d_in[4];
    const int* src2 = (const int*)d_in[5];
    const int* dst2 = (const int*)d_in[6];
    const float* WA0 = (const float*)d_in[7];
    const float* WA1 = (const float*)d_in[8];
    const float* WA2 = (const float*)d_in[9];
    const float* WC = (const float*)d_in[10];
    const float* bC = (const float*)d_in[11];

    const int N = in_sizes[0] / D;  // 100000
    const int E = in_sizes[2];      // 500000

    auto align256 = [](size_t v) { return (v + 255) & ~(size_t)255; };
    char* ws = (char*)d_ws;
    size_t ofs = 0;
    u16* xb = (u16*)(ws + ofs);     ofs = align256(ofs + (size_t)N * D * sizeof(u16));
    int* counts = (int*)(ws + ofs); ofs = align256(ofs + (size_t)3 * N * sizeof(int));
    int* offs = (int*)(ws + ofs);   ofs = align256(ofs + (size_t)3 * (N + 1) * sizeof(int));
    int* cursor = (int*)(ws + ofs); ofs = align256(ofs + (size_t)3 * N * sizeof(int));
    int* eids = (int*)(ws + ofs);   ofs = align256(ofs + (size_t)3 * E * sizeof(int));
    u16* Wp = (u16*)(ws + ofs);     ofs = align256(ofs + (size_t)896 * D * sizeof(u16));
    u16* AG = (u16*)(ws + ofs);

    // node-chunk size limited by remaining workspace (deterministic in ws_size)
    size_t avail = (ws_size > ofs) ? (ws_size - ofs) : 0;
    long long ncMax = (long long)(avail / (768 * sizeof(u16)));
    int Nc = (int)((ncMax / 128) * 128);
    if (Nc > N) Nc = ((N + 127) / 128) * 128;
    if (Nc < 128) Nc = 128;  // minimal fallback

    // prep
    zero_int_kernel<<<512, 256, 0, stream>>>(counts, 3 * N);
    convert_x_kernel<<<1024, 256, 0, stream>>>((const float4*)x, (ushort4*)xb, N * D / 4);

    int cb = (E + 255) / 256;
    count_kernel<<<cb, 256, 0, stream>>>(dst0, counts, E);
    count_kernel<<<cb, 256, 0, stream>>>(dst1, counts + N, E);
    count_kernel<<<cb, 256, 0, stream>>>(dst2, counts + 2 * N, E);

    scan_kernel<<<3, 1024, 0, stream>>>(counts, offs, cursor, N);

    scatter_kernel<<<cb, 256, 0, stream>>>(dst0, cursor, eids, E);
    scatter_kernel<<<cb, 256, 0, stream>>>(dst1, cursor + N, eids + E, E);
    scatter_kernel<<<cb, 256, 0, stream>>>(dst2, cursor + 2 * N, eids + 2 * E, E);

    // B matrix: ks 0-1 = WC^T, 2-3 = WA0, 4-7 = WA1, 8-13 = WA2
    pack_kernel<<<(128 * 16 + 255) / 256, 256, 0, stream>>>(WC, Wp, 128, 1);
    pack_kernel<<<(128 * 16 + 255) / 256, 256, 0, stream>>>(WA0, Wp + 16384, 128, 0);
    pack_kernel<<<(256 * 16 + 255) / 256, 256, 0, stream>>>(WA1, Wp + 32768, 256, 0);
    pack_kernel<<<(384 * 16 + 255) / 256, 256, 0, stream>>>(WA2, Wp + 65536, 384, 0);

    for (int n0 = 0; n0 < N; n0 += Nc) {
        int M = (N - n0 < Nc) ? (N - n0) : Nc;
        int ab = ((M + 3) / 4);
        aggregate_kernel<<<ab, 256, 0, stream>>>(xb, offs, eids, src0, src1, src2,
                                                 AG, n0, M, N, E);
        final_gemm_kernel<<<(M + 127) / 128, 256, 0, stream>>>(xb, AG, Wp, bC,
                                                               (float*)d_out, n0, M);
    }
}

// Round 4
// 544.708 us; speedup vs baseline: 1.7917x; 1.3009x over previous
//
#include <hip/hip_runtime.h>
#include <hip/hip_bf16.h>

typedef unsigned short u16;
typedef __bf16 bf16x8 __attribute__((ext_vector_type(8)));
typedef float floatx4 __attribute__((ext_vector_type(4)));

static constexpr int D = 128;

__device__ inline float bflo(unsigned u) { return __uint_as_float(u << 16); }
__device__ inline float bfhi(unsigned u) { return __uint_as_float(u & 0xffff0000u); }
__device__ inline unsigned packbf(float a, float b) {
    unsigned lo = __hip_bfloat16_raw(__float2bfloat16(a)).x;
    unsigned hi = __hip_bfloat16_raw(__float2bfloat16(b)).x;
    return lo | (hi << 16);
}

// ---------------- zero ints ----------------
__global__ void zero_int_kernel(int* __restrict__ p, int n) {
    int i = blockIdx.x * blockDim.x + threadIdx.x;
    int stride = gridDim.x * blockDim.x;
    for (; i < n; i += stride) p[i] = 0;
}

// ---------------- convert x fp32 -> bf16 ----------------
__global__ void convert_x_kernel(const float4* __restrict__ x, ushort4* __restrict__ xb, int n4) {
    int i = blockIdx.x * blockDim.x + threadIdx.x;
    int stride = gridDim.x * blockDim.x;
    for (; i < n4; i += stride) {
        float4 v = x[i];
        ushort4 o;
        o.x = __hip_bfloat16_raw(__float2bfloat16(v.x)).x;
        o.y = __hip_bfloat16_raw(__float2bfloat16(v.y)).x;
        o.z = __hip_bfloat16_raw(__float2bfloat16(v.z)).x;
        o.w = __hip_bfloat16_raw(__float2bfloat16(v.w)).x;
        xb[i] = o;
    }
}

// ---------------- per-dst counts ----------------
__global__ void count_kernel(const int* __restrict__ dst, int* __restrict__ counts, int E) {
    int i = blockIdx.x * blockDim.x + threadIdx.x;
    if (i < E) atomicAdd(&counts[dst[i]], 1);
}

// ---------------- offsets: wave scan + one atomic per wave ----------------
// CSR segments need only be disjoint+contiguous per node, not sorted.
__global__ __launch_bounds__(256) void offs_kernel(const int* __restrict__ counts,
                                                   int* __restrict__ offs,
                                                   int* __restrict__ cursor,
                                                   int* __restrict__ counters,
                                                   int N, int bpt) {
    int type = blockIdx.x / bpt;
    int n = (blockIdx.x - type * bpt) * 256 + threadIdx.x;
    int lane = threadIdx.x & 63;
    int i = type * N + n;
    int v = (n < N) ? counts[i] : 0;
    int incl = v;
#pragma unroll
    for (int d = 1; d < 64; d <<= 1) {
        int t = __shfl_up(incl, d, 64);
        if (lane >= d) incl += t;
    }
    int total = __shfl(incl, 63, 64);
    int base = 0;
    if (lane == 63) base = atomicAdd(&counters[type], total);
    base = __shfl(base, 63, 64);
    int off = base + incl - v;
    if (n < N) {
        offs[i] = off;
        cursor[i] = off;
    }
}

// ---------------- CSR scatter: store src row-ids directly ----------------
template <int A>
__global__ void scatter_kernel(const int* __restrict__ dst, const int* __restrict__ src,
                               int* __restrict__ cursor, int* __restrict__ csr, int E) {
    int e = blockIdx.x * blockDim.x + threadIdx.x;
    if (e < E) {
        int pos = atomicAdd(&cursor[dst[e]], 1);
#pragma unroll
        for (int s = 0; s < A; ++s) csr[pos * A + s] = src[e * A + s];
    }
}

// ---------------- per-node aggregation: 16-lane row groups, 4 rows in flight ----------------
template <int A>
__device__ inline void agg_type(const u16* __restrict__ xb, const int* __restrict__ csr,
                                int o0, int deg, int lane, u16* __restrict__ outp) {
    const int group = lane >> 4, li = lane & 15;
    float acc[A][8];
#pragma unroll
    for (int s = 0; s < A; ++s)
#pragma unroll
        for (int j = 0; j < 8; ++j) acc[s][j] = 0.f;

    const int items = deg * A;
    const int base = o0 * A;
    for (int c0 = 0; c0 < items; c0 += 64) {
        int rl = 0;
        if (c0 + lane < items) rl = csr[base + c0 + lane];
        int lim = items - c0;
        if (lim > 64) lim = 64;
        int iters = (lim + 3) >> 2;  // uniform trip count across the wave
#pragma unroll 2
        for (int k = 0; k < iters; ++k) {
            int idx = group + 4 * k;
            bool ok = idx < lim;
            int r = __shfl(rl, ok ? idx : 0, 64);  // all lanes active in shfl
            if (ok) {
                const uint4 v = *(const uint4*)(xb + (size_t)r * D + li * 8);
                float f[8];
                f[0] = bflo(v.x); f[1] = bfhi(v.x);
                f[2] = bflo(v.y); f[3] = bfhi(v.y);
                f[4] = bflo(v.z); f[5] = bfhi(v.z);
                f[6] = bflo(v.w); f[7] = bfhi(v.w);
                if constexpr (A == 1) {
#pragma unroll
                    for (int j = 0; j < 8; ++j) acc[0][j] += f[j];
                } else if constexpr (A == 2) {
                    if (((c0 + idx) & 1) == 0) {
#pragma unroll
                        for (int j = 0; j < 8; ++j) acc[0][j] += f[j];
                    } else {
#pragma unroll
                        for (int j = 0; j < 8; ++j) acc[1][j] += f[j];
                    }
                } else {
                    int s = (c0 + idx) % 3;
                    if (s == 0) {
#pragma unroll
                        for (int j = 0; j < 8; ++j) acc[0][j] += f[j];
                    } else if (s == 1) {
#pragma unroll
                        for (int j = 0; j < 8; ++j) acc[1][j] += f[j];
                    } else {
#pragma unroll
                        for (int j = 0; j < 8; ++j) acc[2][j] += f[j];
                    }
                }
            }
        }
    }
    // cross-group reduce (untouched accs are zero, so generic xor-reduce is correct)
#pragma unroll
    for (int s = 0; s < A; ++s)
#pragma unroll
        for (int j = 0; j < 8; ++j) {
            acc[s][j] += __shfl_xor(acc[s][j], 16, 64);
            acc[s][j] += __shfl_xor(acc[s][j], 32, 64);
        }
    float norm = (deg > 0) ? 1.0f / (float)deg : 0.0f;
#pragma unroll
    for (int s = 0; s < A; ++s) {
        if (group == s) {
            uint4 o;
            o.x = packbf(acc[s][0] * norm, acc[s][1] * norm);
            o.y = packbf(acc[s][2] * norm, acc[s][3] * norm);
            o.z = packbf(acc[s][4] * norm, acc[s][5] * norm);
            o.w = packbf(acc[s][6] * norm, acc[s][7] * norm);
            *(uint4*)(outp + s * D + li * 8) = o;
        }
    }
}

__global__ __launch_bounds__(256) void aggregate_kernel(
    const u16* __restrict__ xb, const int* __restrict__ counts, const int* __restrict__ offs,
    const int* __restrict__ csr0, const int* __restrict__ csr1, const int* __restrict__ csr2,
    u16* __restrict__ AG, int n0, int M, int N) {
    int gw = blockIdx.x * 4 + (threadIdx.x >> 6);
    int lane = threadIdx.x & 63;
    if (gw >= 3 * M) return;
    int type = (gw >= 2 * M) ? 2 : (gw >= M) ? 1 : 0;
    int l = gw - type * M;
    int n = n0 + l;
    u16* outp = AG + (size_t)l * 768;
    if (type == 0)
        agg_type<1>(xb, csr0, offs[n], counts[n], lane, outp);
    else if (type == 1)
        agg_type<2>(xb, csr1, offs[N + n], counts[N + n], lane, outp + 128);
    else
        agg_type<3>(xb, csr2, offs[2 * N + n], counts[2 * N + n], lane, outp + 384);
}

// ---------------- pack fp32 weight into bf16 MFMA B-fragment order ----------------
__global__ void pack_kernel(const float* __restrict__ W, u16* __restrict__ out, int K, int transposed) {
    int c = blockIdx.x * blockDim.x + threadIdx.x;
    if (c >= K * 16) return;
    int s = c >> 9, rem = c & 511, t = rem >> 6, l = rem & 63;
    int kbase = 32 * s + ((l >> 4) * 8);
    int n = 16 * t + (l & 15);
#pragma unroll
    for (int j = 0; j < 8; ++j) {
        int k = kbase + j;
        float w = transposed ? W[n * K + k] : W[k * D + n];
        out[(size_t)c * 8 + j] = __hip_bfloat16_raw(__float2bfloat16(w)).x;
    }
}

// ---------------- fused final GEMM: out = [x | AG] @ [WC^T; WA*] + bC ----------------
__global__ __launch_bounds__(256) void final_gemm_kernel(
    const u16* __restrict__ xb, const u16* __restrict__ AG, const u16* __restrict__ Wp,
    const float* __restrict__ bC, float* __restrict__ out, int n0, int M) {
    constexpr int KSTEPS = 14;  // 896 / 64
    alignas(16) __shared__ u16 As[128][72];
    alignas(16) __shared__ u16 Bs[8192];

    const int tid = threadIdx.x;
    const int wave = tid >> 6;
    const int lane = tid & 63;
    const int m0 = blockIdx.x * 128;

    floatx4 acc[2][8];
#pragma unroll
    for (int s = 0; s < 2; ++s)
#pragma unroll
        for (int t = 0; t < 8; ++t) acc[s][t] = floatx4{0.f, 0.f, 0.f, 0.f};

    for (int ks = 0; ks < KSTEPS; ++ks) {
#pragma unroll
        for (int it = 0; it < 4; ++it) {
            int chunk = tid + it * 256;
            int row = chunk >> 3, part = chunk & 7;
            int e = m0 + row;
            const u16* srcp;
            if (ks < 2) {
                int g = (e < M) ? (n0 + e) : n0;
                srcp = xb + (size_t)g * D + ks * 64;
            } else {
                int l = (e < M) ? e : 0;
                srcp = AG + (size_t)l * 768 + (ks - 2) * 64;
            }
            *(uint4*)(&As[row][part * 8]) = *(const uint4*)(srcp + part * 8);
        }
        {
            const uint4* sB = (const uint4*)(Wp + (size_t)ks * 8192);
            uint4* dB = (uint4*)Bs;
#pragma unroll
            for (int it = 0; it < 4; ++it) dB[tid + it * 256] = sB[tid + it * 256];
        }
        __syncthreads();
#pragma unroll
        for (int sub = 0; sub < 2; ++sub) {
            bf16x8 bfrag[8];
#pragma unroll
            for (int t = 0; t < 8; ++t)
                bfrag[t] = *(const bf16x8*)(&Bs[((sub * 8 + t) * 64 + lane) * 8]);
#pragma unroll
            for (int strip = 0; strip < 2; ++strip) {
                int row = wave * 32 + strip * 16 + (lane & 15);
                bf16x8 afrag = *(const bf16x8*)(&As[row][sub * 32 + ((lane >> 4) * 8)]);
#pragma unroll
                for (int t = 0; t < 8; ++t)
                    acc[strip][t] = __builtin_amdgcn_mfma_f32_16x16x32_bf16(
                        afrag, bfrag[t], acc[strip][t], 0, 0, 0);
            }
        }
        __syncthreads();
    }

#pragma unroll
    for (int strip = 0; strip < 2; ++strip) {
#pragma unroll
        for (int r = 0; r < 4; ++r) {
            int row = wave * 32 + strip * 16 + (lane >> 4) * 4 + r;
            int e = m0 + row;
            if (e >= M) continue;
            size_t base = (size_t)(n0 + e) * D;
#pragma unroll
            for (int t = 0; t < 8; ++t) {
                int col = 16 * t + (lane & 15);
                out[base + col] = acc[strip][t][r] + bC[col];
            }
        }
    }
}

extern "C" void kernel_launch(void* const* d_in, const int* in_sizes, int n_in,
                              void* d_out, int out_size, void* d_ws, size_t ws_size,
                              hipStream_t stream) {
    const float* x = (const float*)d_in[0];
    const int* src0 = (const int*)d_in[1];
    const int* dst0 = (const int*)d_in[2];
    const int* src1 = (const int*)d_in[3];
    const int* dst1 = (const int*)d_in[4];
    const int* src2 = (const int*)d_in[5];
    const int* dst2 = (const int*)d_in[6];
    const float* WA0 = (const float*)d_in[7];
    const float* WA1 = (const float*)d_in[8];
    const float* WA2 = (const float*)d_in[9];
    const float* WC = (const float*)d_in[10];
    const float* bC = (const float*)d_in[11];

    const int N = in_sizes[0] / D;  // 100000
    const int E = in_sizes[2];      // 500000

    auto align256 = [](size_t v) { return (v + 255) & ~(size_t)255; };
    char* ws = (char*)d_ws;
    size_t ofs = 0;
    u16* xb = (u16*)(ws + ofs);      ofs = align256(ofs + (size_t)N * D * sizeof(u16));
    int* counts = (int*)(ws + ofs);  ofs = align256(ofs + ((size_t)3 * N + 4) * sizeof(int));
    int* counters = counts + 3 * N;  // 3 ints, zeroed with counts
    int* offs = (int*)(ws + ofs);    ofs = align256(ofs + (size_t)3 * N * sizeof(int));
    int* cursor = (int*)(ws + ofs);  ofs = align256(ofs + (size_t)3 * N * sizeof(int));
    int* csr0 = (int*)(ws + ofs);    // E ints
    int* csr1 = csr0 + E;            // 2E ints
    int* csr2 = csr1 + 2 * E;        // 3E ints
    ofs = align256(ofs + (size_t)6 * E * sizeof(int));
    u16* Wp = (u16*)(ws + ofs);      ofs = align256(ofs + (size_t)896 * D * sizeof(u16));
    u16* AG = (u16*)(ws + ofs);

    size_t avail = (ws_size > ofs) ? (ws_size - ofs) : 0;
    long long ncMax = (long long)(avail / (768 * sizeof(u16)));
    int Nc = (int)((ncMax / 128) * 128);
    if (Nc > N) Nc = ((N + 127) / 128) * 128;
    if (Nc < 128) Nc = 128;

    // prep
    zero_int_kernel<<<512, 256, 0, stream>>>(counts, 3 * N + 4);
    convert_x_kernel<<<1024, 256, 0, stream>>>((const float4*)x, (ushort4*)xb, N * D / 4);

    int cb = (E + 255) / 256;
    count_kernel<<<cb, 256, 0, stream>>>(dst0, counts, E);
    count_kernel<<<cb, 256, 0, stream>>>(dst1, counts + N, E);
    count_kernel<<<cb, 256, 0, stream>>>(dst2, counts + 2 * N, E);

    int bpt = (N + 255) / 256;
    offs_kernel<<<3 * bpt, 256, 0, stream>>>(counts, offs, cursor, counters, N, bpt);

    scatter_kernel<1><<<cb, 256, 0, stream>>>(dst0, src0, cursor, csr0, E);
    scatter_kernel<2><<<cb, 256, 0, stream>>>(dst1, src1, cursor + N, csr1, E);
    scatter_kernel<3><<<cb, 256, 0, stream>>>(dst2, src2, cursor + 2 * N, csr2, E);

    // B matrix: ks 0-1 = WC^T, 2-3 = WA0, 4-7 = WA1, 8-13 = WA2
    pack_kernel<<<(128 * 16 + 255) / 256, 256, 0, stream>>>(WC, Wp, 128, 1);
    pack_kernel<<<(128 * 16 + 255) / 256, 256, 0, stream>>>(WA0, Wp + 16384, 128, 0);
    pack_kernel<<<(256 * 16 + 255) / 256, 256, 0, stream>>>(WA1, Wp + 32768, 256, 0);
    pack_kernel<<<(384 * 16 + 255) / 256, 256, 0, stream>>>(WA2, Wp + 65536, 384, 0);

    for (int n0 = 0; n0 < N; n0 += Nc) {
        int M = (N - n0 < Nc) ? (N - n0) : Nc;
        int ab = (3 * M + 3) / 4;
        aggregate_kernel<<<ab, 256, 0, stream>>>(xb, counts, offs, csr0, csr1, csr2,
                                                 AG, n0, M, N);
        final_gemm_kernel<<<(M + 127) / 128, 256, 0, stream>>>(xb, AG, Wp, bC,
                                                               (float*)d_out, n0, M);
    }
}